// Round 10
// baseline (286.201 us; speedup 1.0000x reference)
//
#include <hip/hip_runtime.h>
#include <hip/hip_bf16.h>
#include <hip/hip_fp16.h>
#include <math.h>

// LGCN layer. R9 post-mortem: reducer was residency-capped by its own grid
// (1563 blocks = 6.1/CU < the 8/CU cap) and gather-byte heavy (f32 rows =
// 4 lines/edge, 12.8MB table vs 4MB/XCD L2). R10:
//   - reducer sub-buckets NB=16 -> grid 3125 (backfillable), 8KB LDS,
//     8 blocks x 4 waves = 32 waves/CU (R4 evidence: wave count is the lever)
//   - f16 feat table for message gather (128B rows, 6.4MB table); epilogue f32
//   - scatter parents SHIFT 7 (C=391), 1024-thr blocks, 84B runs
// Entry: x = src(16b) | dl_parent(7b)<<16 ; y = att f32.

#define D 64
#define SHIFT_S 7                 // scatter parent bucket = 128 dst nodes
#define CS_MAX 512                // max parents (N <= 65536)
#define SHIFT_R 4                 // reducer sub-bucket = 16 dst nodes
#define NBR 16
#define CAP 1024                  // LDS capacity per sub-bucket window (mean 512)
#define CHUNK 4096                // edges per scatter block

// ------- kernel 1: attention scalars + f16 feat table + coarse hist ---------
__global__ __launch_bounds__(256) void precompute_att(
    const float* __restrict__ feat, const float* __restrict__ lin_w,
    const float* __restrict__ lin_b, const int* __restrict__ edst,
    float* __restrict__ s1, float* __restrict__ s2, __half* __restrict__ fh,
    int* __restrict__ ghist, int Cs, int N, int E) {
  __shared__ int h[CS_MAX];
  for (int i = threadIdx.x; i < Cs; i += 256) h[i] = 0;
  __syncthreads();

  const int E4 = E >> 2;
  const int4* edst4 = (const int4*)edst;
  for (int i4 = blockIdx.x * 256 + threadIdx.x; i4 < E4; i4 += gridDim.x * 256) {
    const int4 d = edst4[i4];
    atomicAdd(&h[d.x >> SHIFT_S], 1);
    atomicAdd(&h[d.y >> SHIFT_S], 1);
    atomicAdd(&h[d.z >> SHIFT_S], 1);
    atomicAdd(&h[d.w >> SHIFT_S], 1);
  }
  if (blockIdx.x == 0 && threadIdx.x == 0) {
    for (int e = E4 << 2; e < E; ++e) atomicAdd(&h[edst[e] >> SHIFT_S], 1);
  }

  const int lane = threadIdx.x & 63;
  const int wid  = (blockIdx.x * blockDim.x + threadIdx.x) >> 6;
  const int nw   = (gridDim.x * blockDim.x) >> 6;
  const float w1 = lin_w[lane];
  const float w2 = lin_w[64 + lane];
  const float b  = lin_b[0];
  for (int i = wid; i < N; i += nw) {
    const float f = feat[(size_t)i * D + lane];
    if (fh) fh[(size_t)i * D + lane] = __float2half(f);
    float v1 = f * w1;
    float v2 = f * w2;
    #pragma unroll
    for (int off = 32; off > 0; off >>= 1) {
      v1 += __shfl_down(v1, off, 64);
      v2 += __shfl_down(v2, off, 64);
    }
    if (lane == 0) {
      s1[i] = v1 + b;   // fold bias into s1
      s2[i] = v2;
    }
  }

  __syncthreads();
  for (int i = threadIdx.x; i < Cs; i += 256) {
    const int v = h[i];
    if (v) atomicAdd(&ghist[i], v);   // ghist pre-zeroed by memsetAsync
  }
}

// ------- kernel 2: exclusive scan of Cs<=512 parent counts ----------------
__global__ __launch_bounds__(512) void scan_coarse(
    const int* __restrict__ ghist, int* __restrict__ bstart,
    int* __restrict__ gcur, int Cs) {
  __shared__ int tot[512];
  const int t = threadIdx.x;
  const int v = (t < Cs) ? ghist[t] : 0;
  tot[t] = v;
  __syncthreads();
  for (int off = 1; off < 512; off <<= 1) {
    int u = tot[t] + ((t >= off) ? tot[t - off] : 0);
    __syncthreads();
    tot[t] = u;
    __syncthreads();
  }
  if (t < Cs) {
    bstart[t] = tot[t] - v;
    gcur[t]   = tot[t] - v;
  }
}

// ---------------- kernel 3: coarse scatter (parents of 128 nodes) -----------
__global__ __launch_bounds__(1024) void coarse_scatter(
    const int* __restrict__ esrc, const int* __restrict__ edst,
    const float* __restrict__ s1, const float* __restrict__ s2,
    int* __restrict__ gcur, uint2* __restrict__ ebuf, int E, int Cs) {
  __shared__ int h[CS_MAX];
  __shared__ int cur[CS_MAX];
  __shared__ int bl[CS_MAX];
  for (int i = threadIdx.x; i < Cs; i += 1024) h[i] = 0;
  __syncthreads();
  const int E4 = E >> 2;
  const int4* edst4 = (const int4*)edst;
  const int4* esrc4 = (const int4*)esrc;
  const int idx = blockIdx.x * (CHUNK >> 2) + threadIdx.x;   // one int4/thread
  const bool tail0 = (blockIdx.x == 0) && (threadIdx.x == 0);

  if (idx < E4) {
    const int4 d = edst4[idx];
    atomicAdd(&h[d.x >> SHIFT_S], 1);
    atomicAdd(&h[d.y >> SHIFT_S], 1);
    atomicAdd(&h[d.z >> SHIFT_S], 1);
    atomicAdd(&h[d.w >> SHIFT_S], 1);
  }
  if (tail0) for (int e = E4 << 2; e < E; ++e) atomicAdd(&h[edst[e] >> SHIFT_S], 1);
  __syncthreads();
  for (int i = threadIdx.x; i < Cs; i += 1024) {
    const int v = h[i];
    bl[i] = v ? atomicAdd(&gcur[i], v) : 0;
    cur[i] = 0;
  }
  __syncthreads();

  if (idx < E4) {
    const int4 s = esrc4[idx];
    const int4 d = edst4[idx];
    const int ss[4] = {s.x, s.y, s.z, s.w};
    const int dd[4] = {d.x, d.y, d.z, d.w};
    float a1[4], a2[4];
    #pragma unroll
    for (int j = 0; j < 4; ++j) a1[j] = s1[ss[j]];   // independent gathers
    #pragma unroll
    for (int j = 0; j < 4; ++j) a2[j] = s2[dd[j]];
    #pragma unroll
    for (int j = 0; j < 4; ++j) {
      const float a = 1.0f / (1.0f + __expf(-fmaxf(a1[j] + a2[j], 0.0f)));
      const int bk = dd[j] >> SHIFT_S;
      const int r  = atomicAdd(&cur[bk], 1);
      ebuf[bl[bk] + r] = make_uint2(
          (unsigned)ss[j] | ((unsigned)(dd[j] & 127) << 16), __float_as_uint(a));
    }
  }
  if (tail0) {
    for (int e = E4 << 2; e < E; ++e) {
      const int sj = esrc[e], dj = edst[e];
      const float a = 1.0f / (1.0f + __expf(-fmaxf(s1[sj] + s2[dj], 0.0f)));
      const int bk = dj >> SHIFT_S;
      const int r  = atomicAdd(&cur[bk], 1);
      ebuf[bl[bk] + r] = make_uint2(
          (unsigned)sj | ((unsigned)(dj & 127) << 16), __float_as_uint(a));
    }
  }
}

// ---------------- kernel 4: sub-bucket sort + register reduce ----------------
// Block g handles sub-bucket g (16 nodes); parent = g>>3, filters the parent's
// range for dl>>4 == (g&7). Fast path: whole sub-bucket (mean 512 <= CAP) in
// one window. 8KB LDS -> 8 blocks x 4 waves = 32 waves/CU; grid 3125 backfills.
__global__ __launch_bounds__(256, 8) void bucket_reduce(
    const float* __restrict__ feat, const __half* __restrict__ fh,
    const float* __restrict__ norm, const int* __restrict__ bstart,
    const int* __restrict__ gcur, const uint2* __restrict__ ebuf,
    const float* __restrict__ W_rel, const float* __restrict__ loop_w,
    const float* __restrict__ evolve_w, float* __restrict__ out, int N) {
  __shared__ uint2 sdata[CAP];    // 8 KB
  __shared__ int   hist[NBR];
  __shared__ int   roff[NBR];     // starts -> consumed into ends by place pass
  __shared__ int   scnt;

  const int tid    = threadIdx.x;
  const int lane   = tid & 63;
  const int wv     = __builtin_amdgcn_readfirstlane(tid >> 6);  // 0..3
  const int g      = blockIdx.x;
  const int parent = g >> 3;
  const int sub    = g & 7;
  const int n0     = g << SHIFT_R;
  const int pbeg   = __builtin_amdgcn_readfirstlane(bstart[parent]);
  const int pend   = __builtin_amdgcn_readfirstlane(gcur[parent]);

  float acc[4];
  int   deg[4];
  #pragma unroll
  for (int j = 0; j < 4; ++j) { acc[j] = 0.0f; deg[j] = 0; }

  // pass A: histogram of this sub-bucket over the parent range
  if (tid < NBR) hist[tid] = 0;
  __syncthreads();
  for (int i = pbeg + tid; i < pend; i += 256) {
    const unsigned dl = (ebuf[i].x >> 16) & 127u;
    if ((int)(dl >> 4) == sub) atomicAdd(&hist[dl & 15u], 1);
  }
  __syncthreads();
  if (tid < NBR) {
    const int v = hist[tid];
    int incl = v;
    #pragma unroll
    for (int off = 1; off < NBR; off <<= 1) {
      const int o = __shfl_up(incl, off, 64);
      if (tid >= off) incl += o;
    }
    roff[tid] = incl - v;
    if (tid == NBR - 1) scnt = incl;
  }
  __syncthreads();
  const int cnt = scnt;                       // wave-uniform (LDS broadcast)
  const bool fast = (cnt <= CAP);
  const int winW = fast ? (pend - pbeg > 0 ? pend - pbeg : 1) : CAP;

  for (int w = pbeg; w < pend; w += winW) {
    const int we = min(w + winW, pend);
    if (!fast) {                               // rebuild hist for this window
      __syncthreads();
      if (tid < NBR) hist[tid] = 0;
      __syncthreads();
      for (int i = w + tid; i < we; i += 256) {
        const unsigned dl = (ebuf[i].x >> 16) & 127u;
        if ((int)(dl >> 4) == sub) atomicAdd(&hist[dl & 15u], 1);
      }
      __syncthreads();
      if (tid < NBR) {
        const int v = hist[tid];
        int incl = v;
        #pragma unroll
        for (int off = 1; off < NBR; off <<= 1) {
          const int o = __shfl_up(incl, off, 64);
          if (tid >= off) incl += o;
        }
        roff[tid] = incl - v;
      }
      __syncthreads();
    }
    // place pass: sorted placement into sdata; roff consumed -> run ends
    for (int i = w + tid; i < we; i += 256) {
      const uint2 e = ebuf[i];
      const unsigned dl = (e.x >> 16) & 127u;
      if ((int)(dl >> 4) == sub) {
        const int pos = atomicAdd(&roff[dl & 15u], 1);
        sdata[pos] = e;
      }
    }
    __syncthreads();
    // register accumulate: wave wv -> nodes wv*4 .. wv*4+3
    #pragma unroll
    for (int jj = 0; jj < 4; ++jj) {
      const int j  = wv * 4 + jj;
      const int pb = __builtin_amdgcn_readfirstlane(j == 0 ? 0 : roff[j - 1]);
      const int pe = __builtin_amdgcn_readfirstlane(roff[j]);
      deg[jj] += pe - pb;
      int p = pb;
      if (fh) {
        for (; p + 16 <= pe; p += 16) {
          uint2 ent[16];
          #pragma unroll
          for (int q = 0; q < 16; ++q) ent[q] = sdata[p + q];
          float ff[16];
          #pragma unroll
          for (int q = 0; q < 16; ++q)
            ff[q] = __half2float(fh[(size_t)(ent[q].x & 0xFFFFu) * D + lane]);
          #pragma unroll
          for (int q = 0; q < 16; ++q)
            acc[jj] += __uint_as_float(ent[q].y) * ff[q];
        }
        for (; p < pe; ++p) {
          const uint2 en = sdata[p];
          acc[jj] += __uint_as_float(en.y) *
                     __half2float(fh[(size_t)(en.x & 0xFFFFu) * D + lane]);
        }
      } else {
        for (; p + 16 <= pe; p += 16) {
          uint2 ent[16];
          #pragma unroll
          for (int q = 0; q < 16; ++q) ent[q] = sdata[p + q];
          float ff[16];
          #pragma unroll
          for (int q = 0; q < 16; ++q)
            ff[q] = feat[(size_t)(ent[q].x & 0xFFFFu) * D + lane];
          #pragma unroll
          for (int q = 0; q < 16; ++q)
            acc[jj] += __uint_as_float(ent[q].y) * ff[q];
        }
        for (; p < pe; ++p) {
          const uint2 en = sdata[p];
          acc[jj] += __uint_as_float(en.y) *
                     feat[(size_t)(en.x & 0xFFFFu) * D + lane];
        }
      }
    }
    __syncthreads();   // sdata reuse safety for (rare) next window
  }

  // epilogue: matvecs + tanh for this wave's 4 nodes (exact f32 feat)
  #pragma unroll
  for (int jj = 0; jj < 4; ++jj) {
    const int n = n0 + wv * 4 + jj;
    if (n >= N) break;
    const float f  = feat[(size_t)n * D + lane];
    const float nr = norm[n];
    float nf, lm = 0.0f;
    if (deg[jj] > 0) {
      const float pa = acc[jj];
      float a1 = 0.0f;
      #pragma unroll 8
      for (int k = 0; k < D; ++k) {
        const float fb = __shfl(f, k, 64);
        const float pb = __shfl(pa, k, 64);
        a1 += pb * W_rel[k * D + lane];
        lm += fb * loop_w[k * D + lane];
      }
      nf = a1 * nr;
    } else {
      #pragma unroll 8
      for (int k = 0; k < D; ++k) {
        const float fb = __shfl(f, k, 64);
        lm += fb * evolve_w[k * D + lane];
      }
      nf = f * nr;   // zero in-degree keeps old feat
    }
    out[(size_t)n * D + lane] = tanhf(nf + lm);
  }
}

extern "C" void kernel_launch(void* const* d_in, const int* in_sizes, int n_in,
                              void* d_out, int out_size, void* d_ws, size_t ws_size,
                              hipStream_t stream) {
  const float* feat     = (const float*)d_in[0];
  const float* norm     = (const float*)d_in[1];
  const int*   esrc     = (const int*)d_in[2];
  const int*   edst     = (const int*)d_in[3];
  // d_in[4] = etype: no-op permutation per the reference
  const float* W_rel    = (const float*)d_in[5];
  const float* lin_w    = (const float*)d_in[6];
  const float* lin_b    = (const float*)d_in[7];
  const float* loop_w   = (const float*)d_in[8];
  const float* evolve_w = (const float*)d_in[9];
  float* out = (float*)d_out;

  const int N = in_sizes[1];   // norm is [N]   (N <= 65536 assumed: 16b src)
  const int E = in_sizes[2];   // edge_src is [E]
  const int Cs = (N + (1 << SHIFT_S) - 1) >> SHIFT_S;   // 391 parents
  const int Cr = (N + NBR - 1) >> SHIFT_R;              // 3125 sub-buckets

  // layout: s1[N] | s2[N] | fh[N*D] (optional) | bstart | gcur | ghist | ebuf[E]
  const size_t fh_bytes = (size_t)N * D * sizeof(__half);
  const size_t base     = (size_t)N * 2 * sizeof(float);
  const size_t tab      = (size_t)CS_MAX * sizeof(int);
  const size_t need_h   = base + fh_bytes + 3 * tab + (size_t)E * sizeof(uint2);
  const bool   use_h    = ws_size >= need_h;

  char* p = (char*)d_ws;
  float*  s1     = (float*)p;                 p += (size_t)N * sizeof(float);
  float*  s2     = (float*)p;                 p += (size_t)N * sizeof(float);
  __half* fh     = nullptr;
  if (use_h) { fh = (__half*)p;               p += fh_bytes; }
  int*    bstart = (int*)p;                   p += tab;
  int*    gcur   = (int*)p;                   p += tab;
  int*    ghist  = (int*)p;                   p += tab;
  uint2*  ebuf   = (uint2*)p;

  const int eblocks = (E + CHUNK - 1) / CHUNK;   // 391 for E=1.6M

  hipMemsetAsync(ghist, 0, (size_t)Cs * sizeof(int), stream);
  precompute_att<<<512, 256, 0, stream>>>(feat, lin_w, lin_b, edst,
                                          s1, s2, fh, ghist, Cs, N, E);
  scan_coarse<<<1, 512, 0, stream>>>(ghist, bstart, gcur, Cs);
  coarse_scatter<<<eblocks, 1024, 0, stream>>>(esrc, edst, s1, s2, gcur,
                                               ebuf, E, Cs);
  bucket_reduce<<<Cr, 256, 0, stream>>>(feat, fh, norm, bstart, gcur, ebuf,
                                        W_rel, loop_w, evolve_w, out, N);
}

// Round 11
// 277.520 us; speedup vs baseline: 1.0313x; 1.0313x over previous
//
#include <hip/hip_runtime.h>
#include <hip/hip_bf16.h>
#include <hip/hip_fp16.h>
#include <math.h>

// LGCN layer, coarse-bucket counting sort + fused in-LDS sort/reduce.
// R10 post-mortem: (a) sub-bucket filtering re-scanned each parent range 16x
//     (+205MB ebuf reads, ate the f16 saving); (b) VGPR=32 -> gather pipeline
//     depth ~2, each wave pays full mem latency per edge (1100 cyc/edge/wave).
// R11: R9 single-pass bucket structure (SHIFT 5, grid 1563) + f16 gather table
//     + __launch_bounds__(256,4) so the reducer can hold a ~16-deep gather
//     pipeline in registers (throughput = waves/CU x depth / latency).

#define D 64
#define SHIFT 5
#define NB (1 << SHIFT)          // dst nodes per bucket (32)
#define CMAX 2048                // max buckets (requires N <= 65536)
#define CHUNK 4096               // edges per block in scatter
#define CAP 2048                 // LDS edge capacity (bucket mean 1024)

// ------- kernel 1: attention scalars + f16 feat table + coarse hist ---------
__global__ __launch_bounds__(256) void precompute_att(
    const float* __restrict__ feat, const float* __restrict__ lin_w,
    const float* __restrict__ lin_b, const int* __restrict__ edst,
    float* __restrict__ s1, float* __restrict__ s2, __half* __restrict__ fh,
    int* __restrict__ ghist, int C, int N, int E) {
  __shared__ int h[CMAX];
  for (int i = threadIdx.x; i < C; i += 256) h[i] = 0;
  __syncthreads();

  const int E4 = E >> 2;
  const int4* edst4 = (const int4*)edst;
  for (int i4 = blockIdx.x * 256 + threadIdx.x; i4 < E4; i4 += gridDim.x * 256) {
    const int4 d = edst4[i4];
    atomicAdd(&h[d.x >> SHIFT], 1);
    atomicAdd(&h[d.y >> SHIFT], 1);
    atomicAdd(&h[d.z >> SHIFT], 1);
    atomicAdd(&h[d.w >> SHIFT], 1);
  }
  if (blockIdx.x == 0 && threadIdx.x == 0) {      // E%4 tail
    for (int e = E4 << 2; e < E; ++e) atomicAdd(&h[edst[e] >> SHIFT], 1);
  }

  const int lane = threadIdx.x & 63;
  const int wid  = (blockIdx.x * blockDim.x + threadIdx.x) >> 6;
  const int nw   = (gridDim.x * blockDim.x) >> 6;
  const float w1 = lin_w[lane];
  const float w2 = lin_w[64 + lane];
  const float b  = lin_b[0];
  for (int i = wid; i < N; i += nw) {
    const float f = feat[(size_t)i * D + lane];
    if (fh) fh[(size_t)i * D + lane] = __float2half(f);
    float v1 = f * w1;
    float v2 = f * w2;
    #pragma unroll
    for (int off = 32; off > 0; off >>= 1) {
      v1 += __shfl_down(v1, off, 64);
      v2 += __shfl_down(v2, off, 64);
    }
    if (lane == 0) {
      s1[i] = v1 + b;   // fold bias into s1
      s2[i] = v2;
    }
  }

  __syncthreads();
  for (int i = threadIdx.x; i < C; i += 256) {
    const int v = h[i];
    if (v) atomicAdd(&ghist[i], v);   // ghist pre-zeroed by memsetAsync
  }
}

// ------- kernel 2: exclusive scan of C<=2048 bucket counts (2 items/thread) --
__global__ __launch_bounds__(1024) void scan_coarse(
    const int* __restrict__ ghist, int* __restrict__ bstart,
    int* __restrict__ gcur, int C) {
  __shared__ int tot[1024];
  const int t = threadIdx.x;
  const int i0 = 2 * t, i1 = 2 * t + 1;
  const int v0 = (i0 < C) ? ghist[i0] : 0;
  const int v1 = (i1 < C) ? ghist[i1] : 0;
  const int s = v0 + v1;
  tot[t] = s;
  __syncthreads();
  for (int off = 1; off < 1024; off <<= 1) {
    int u = tot[t] + ((t >= off) ? tot[t - off] : 0);
    __syncthreads();
    tot[t] = u;
    __syncthreads();
  }
  const int excl = tot[t] - s;
  if (i0 < C) { bstart[i0] = excl;      gcur[i0] = excl; }
  if (i1 < C) { bstart[i1] = excl + v0; gcur[i1] = excl + v0; }
}

// ---------------- kernel 3: coarse scatter, LDS-staged runs ----------------
// Each block reserves one contiguous run per bucket (returning global atomic
// on gcur) and writes its chunk's edges grouped. Runs are temporally dense so
// ebuf lines fill while L2-resident. Entry: x = src | dl<<26, y = att f32.
__global__ __launch_bounds__(256) void coarse_scatter(
    const int* __restrict__ esrc, const int* __restrict__ edst,
    const float* __restrict__ s1, const float* __restrict__ s2,
    int* __restrict__ gcur, uint2* __restrict__ ebuf, int E, int C) {
  __shared__ int h[CMAX];
  __shared__ int cur[CMAX];
  __shared__ int bl[CMAX];
  for (int i = threadIdx.x; i < C; i += 256) h[i] = 0;
  __syncthreads();
  const int E4 = E >> 2;
  const int4* edst4 = (const int4*)edst;
  const int4* esrc4 = (const int4*)esrc;
  const int b4 = blockIdx.x * (CHUNK >> 2);
  const bool tail0 = (blockIdx.x == 0) && (threadIdx.x == 0);

  #pragma unroll
  for (int k = 0; k < CHUNK / 1024; ++k) {
    const int i4 = b4 + threadIdx.x + 256 * k;
    if (i4 < E4) {
      const int4 d = edst4[i4];
      atomicAdd(&h[d.x >> SHIFT], 1);
      atomicAdd(&h[d.y >> SHIFT], 1);
      atomicAdd(&h[d.z >> SHIFT], 1);
      atomicAdd(&h[d.w >> SHIFT], 1);
    }
  }
  if (tail0) for (int e = E4 << 2; e < E; ++e) atomicAdd(&h[edst[e] >> SHIFT], 1);
  __syncthreads();
  for (int i = threadIdx.x; i < C; i += 256) {
    const int v = h[i];
    bl[i] = v ? atomicAdd(&gcur[i], v) : 0;
    cur[i] = 0;
  }
  __syncthreads();

  #pragma unroll
  for (int k = 0; k < CHUNK / 1024; ++k) {
    const int i4 = b4 + threadIdx.x + 256 * k;
    if (i4 < E4) {
      const int4 s = esrc4[i4];
      const int4 d = edst4[i4];
      const int ss[4] = {s.x, s.y, s.z, s.w};
      const int dd[4] = {d.x, d.y, d.z, d.w};
      float a1[4], a2[4];
      #pragma unroll
      for (int j = 0; j < 4; ++j) a1[j] = s1[ss[j]];   // independent gathers
      #pragma unroll
      for (int j = 0; j < 4; ++j) a2[j] = s2[dd[j]];
      #pragma unroll
      for (int j = 0; j < 4; ++j) {
        const float a = 1.0f / (1.0f + __expf(-fmaxf(a1[j] + a2[j], 0.0f)));
        const int bk = dd[j] >> SHIFT;
        const int r  = atomicAdd(&cur[bk], 1);
        ebuf[bl[bk] + r] =
            make_uint2((unsigned)ss[j] | ((unsigned)(dd[j] & (NB - 1)) << 26),
                       __float_as_uint(a));
      }
    }
  }
  if (tail0) {
    for (int e = E4 << 2; e < E; ++e) {
      const int sj = esrc[e], dj = edst[e];
      const float a = 1.0f / (1.0f + __expf(-fmaxf(s1[sj] + s2[dj], 0.0f)));
      const int bk = dj >> SHIFT;
      const int r  = atomicAdd(&cur[bk], 1);
      ebuf[bl[bk] + r] =
          make_uint2((unsigned)sj | ((unsigned)(dj & (NB - 1)) << 26),
                     __float_as_uint(a));
    }
  }
}

// ---------------- kernel 4: in-LDS counting sort + register reduce ----------
// One block (256 thr, 4 waves) per bucket of NB=32 dst nodes; single pass over
// its OWN range only. __launch_bounds__(256,4): <=128 VGPR so the unroll-16
// gather loop can keep ~16 loads in flight (depth is the R11 lever).
__global__ __launch_bounds__(256, 4) void bucket_reduce(
    const float* __restrict__ feat, const __half* __restrict__ fh,
    const float* __restrict__ norm, const int* __restrict__ bstart,
    const int* __restrict__ gcur, const uint2* __restrict__ ebuf,
    const float* __restrict__ W_rel, const float* __restrict__ loop_w,
    const float* __restrict__ evolve_w, float* __restrict__ out, int N) {
  __shared__ uint2 sdata[CAP];    // sorted entries, 16 KB
  __shared__ int   hist[NB];
  __shared__ int   roff[NB];      // exclusive starts -> consumed into ends

  const int tid  = threadIdx.x;
  const int lane = tid & 63;
  const int wv   = __builtin_amdgcn_readfirstlane(tid >> 6);   // 0..3
  const int b    = blockIdx.x;
  const int n0   = b << SHIFT;
  const int beg  = __builtin_amdgcn_readfirstlane(bstart[b]);
  const int end  = __builtin_amdgcn_readfirstlane(gcur[b]);    // bucket end

  float acc[NB / 4];
  int   deg[NB / 4];
  #pragma unroll
  for (int j = 0; j < NB / 4; ++j) { acc[j] = 0.0f; deg[j] = 0; }

  for (int cb = beg; cb < end; cb += CAP) {       // single chunk in practice
    const int ccnt = min(CAP, end - cb);
    __syncthreads();                               // protect prev sdata/roff
    if (tid < NB) hist[tid] = 0;
    __syncthreads();
    // pass 1: histogram (dl only; coalesced global read)
    for (int i = tid; i < ccnt; i += 256) {
      const unsigned x = ebuf[cb + i].x;
      atomicAdd(&hist[x >> 26], 1);
    }
    __syncthreads();
    // lanes 0..NB-1 of wave 0: shfl exclusive scan -> roff (starts)
    if (tid < NB) {
      const int v = hist[tid];
      int incl = v;
      #pragma unroll
      for (int off = 1; off < NB; off <<= 1) {
        const int o = __shfl_up(incl, off, 64);
        if (tid >= off) incl += o;
      }
      roff[tid] = incl - v;
    }
    __syncthreads();
    // pass 2: rank atomic on roff + direct sorted placement (re-read global)
    for (int i = tid; i < ccnt; i += 256) {
      const uint2 e = ebuf[cb + i];
      const int pos = atomicAdd(&roff[e.x >> 26], 1);
      sdata[pos] = e;
    }
    __syncthreads();
    // register accumulate: wave wv -> nodes wv*8 .. wv*8+7; 16 loads in flight
    #pragma unroll
    for (int jj = 0; jj < NB / 4; ++jj) {
      const int j  = wv * (NB / 4) + jj;
      const int pb = __builtin_amdgcn_readfirstlane(j == 0 ? 0 : roff[j - 1]);
      const int pe = __builtin_amdgcn_readfirstlane(roff[j]);
      deg[jj] += pe - pb;
      int p = pb;
      if (fh) {
        for (; p + 16 <= pe; p += 16) {
          uint2 ent[16];
          #pragma unroll
          for (int q = 0; q < 16; ++q) ent[q] = sdata[p + q];
          float ff[16];
          #pragma unroll
          for (int q = 0; q < 16; ++q)
            ff[q] = __half2float(
                fh[(size_t)(ent[q].x & 0x03FFFFFFu) * D + lane]);
          #pragma unroll
          for (int q = 0; q < 16; ++q)
            acc[jj] += __uint_as_float(ent[q].y) * ff[q];
        }
        for (; p + 4 <= pe; p += 4) {
          uint2 ent[4];
          #pragma unroll
          for (int q = 0; q < 4; ++q) ent[q] = sdata[p + q];
          #pragma unroll
          for (int q = 0; q < 4; ++q)
            acc[jj] += __uint_as_float(ent[q].y) *
                       __half2float(
                           fh[(size_t)(ent[q].x & 0x03FFFFFFu) * D + lane]);
        }
        for (; p < pe; ++p) {
          const uint2 en = sdata[p];
          acc[jj] += __uint_as_float(en.y) *
                     __half2float(fh[(size_t)(en.x & 0x03FFFFFFu) * D + lane]);
        }
      } else {
        for (; p + 16 <= pe; p += 16) {
          uint2 ent[16];
          #pragma unroll
          for (int q = 0; q < 16; ++q) ent[q] = sdata[p + q];
          float ff[16];
          #pragma unroll
          for (int q = 0; q < 16; ++q)
            ff[q] = feat[(size_t)(ent[q].x & 0x03FFFFFFu) * D + lane];
          #pragma unroll
          for (int q = 0; q < 16; ++q)
            acc[jj] += __uint_as_float(ent[q].y) * ff[q];
        }
        for (; p < pe; ++p) {
          const uint2 en = sdata[p];
          acc[jj] += __uint_as_float(en.y) *
                     feat[(size_t)(en.x & 0x03FFFFFFu) * D + lane];
        }
      }
    }
  }

  // epilogue: matvecs + tanh for this wave's 8 nodes (exact f32 feat)
  #pragma unroll
  for (int jj = 0; jj < NB / 4; ++jj) {
    const int n = n0 + wv * (NB / 4) + jj;
    if (n >= N) break;
    const float f  = feat[(size_t)n * D + lane];
    const float nr = norm[n];
    float nf, lm = 0.0f;
    if (deg[jj] > 0) {
      const float pa = acc[jj];
      float a1 = 0.0f;
      #pragma unroll 8
      for (int k = 0; k < D; ++k) {
        const float fb = __shfl(f, k, 64);
        const float pb = __shfl(pa, k, 64);
        a1 += pb * W_rel[k * D + lane];
        lm += fb * loop_w[k * D + lane];
      }
      nf = a1 * nr;
    } else {
      #pragma unroll 8
      for (int k = 0; k < D; ++k) {
        const float fb = __shfl(f, k, 64);
        lm += fb * evolve_w[k * D + lane];
      }
      nf = f * nr;   // zero in-degree keeps old feat
    }
    out[(size_t)n * D + lane] = tanhf(nf + lm);
  }
}

extern "C" void kernel_launch(void* const* d_in, const int* in_sizes, int n_in,
                              void* d_out, int out_size, void* d_ws, size_t ws_size,
                              hipStream_t stream) {
  const float* feat     = (const float*)d_in[0];
  const float* norm     = (const float*)d_in[1];
  const int*   esrc     = (const int*)d_in[2];
  const int*   edst     = (const int*)d_in[3];
  // d_in[4] = etype: no-op permutation per the reference
  const float* W_rel    = (const float*)d_in[5];
  const float* lin_w    = (const float*)d_in[6];
  const float* lin_b    = (const float*)d_in[7];
  const float* loop_w   = (const float*)d_in[8];
  const float* evolve_w = (const float*)d_in[9];
  float* out = (float*)d_out;

  const int N = in_sizes[1];   // norm is [N]   (N <= 65536: src fits 26 bits)
  const int E = in_sizes[2];   // edge_src is [E]
  const int C = (N + NB - 1) >> SHIFT;   // 1563 for N=50000

  // layout: s1[N] | s2[N] | fh[N*D] (optional) | bstart | gcur | ghist | ebuf[E]
  const size_t fh_bytes = (size_t)N * D * sizeof(__half);
  const size_t tab      = (size_t)CMAX * sizeof(int);
  const size_t need_h   = (size_t)N * 2 * sizeof(float) + fh_bytes + 3 * tab +
                          (size_t)E * sizeof(uint2);
  const bool   use_h    = ws_size >= need_h;

  char* p = (char*)d_ws;
  float*  s1     = (float*)p;                 p += (size_t)N * sizeof(float);
  float*  s2     = (float*)p;                 p += (size_t)N * sizeof(float);
  __half* fh     = nullptr;
  if (use_h) { fh = (__half*)p;               p += fh_bytes; }
  int*    bstart = (int*)p;                   p += tab;
  int*    gcur   = (int*)p;                   p += tab;
  int*    ghist  = (int*)p;                   p += tab;
  uint2*  ebuf   = (uint2*)p;

  const int eblocks = (E + CHUNK - 1) / CHUNK;   // 391 for E=1.6M

  hipMemsetAsync(ghist, 0, (size_t)C * sizeof(int), stream);
  precompute_att<<<512, 256, 0, stream>>>(feat, lin_w, lin_b, edst,
                                          s1, s2, fh, ghist, C, N, E);
  scan_coarse<<<1, 1024, 0, stream>>>(ghist, bstart, gcur, C);
  coarse_scatter<<<eblocks, 256, 0, stream>>>(esrc, edst, s1, s2, gcur,
                                              ebuf, E, C);
  bucket_reduce<<<C, 256, 0, stream>>>(feat, fh, norm, bstart, gcur, ebuf,
                                       W_rel, loop_w, evolve_w, out, N);
}